// Round 4
// baseline (12298.845 us; speedup 1.0000x reference)
//
#include <hip/hip_runtime.h>
#include <stdint.h>

#define N_NODES 100000
#define N_EDGES 3200000
#define IN_FEATS 500
#define HID 64
#define CLS 40
#define KHOPS 10
#define KT 32
#define NRANGE 8
#define NBKT 13          // src buckets: src>>13, 8192 nodes = 2MB of lastr per bucket
#define BSHIFT 13
#define RPW 13           // dst rows per wave (8192 waves x 13 >= 100000)
#define NOFF2 (N_NODES * NBKT)       // 1,300,000 (bucket,dst) bins
#define M2 (NOFF2 + 1)               // scan length
#define SCAN_BS 256
#define SCAN_NBLK2 ((M2 + SCAN_BS - 1) / SCAN_BS)   // 5079
#define SCANB_T 1024
#define SCANB_CH ((SCAN_NBLK2 + SCANB_T - 1) / SCANB_T)  // 5

// ---------------- generic zero ----------------
__global__ void zero_kernel(float4* __restrict__ p, size_t n4) {
  size_t i = (size_t)blockIdx.x * blockDim.x + threadIdx.x;
  size_t stride = (size_t)gridDim.x * blockDim.x;
  float4 z = make_float4(0.f, 0.f, 0.f, 0.f);
  for (; i < n4; i += stride) p[i] = z;
}

// ---------------- CSR build over (bucket, dst) keys ----------------
// key = (src>>13)*N_NODES + dst  -> bucket-major, dst ascending within bucket.
// Partition edges by SRC range: each r's atomics confined to ~1-2 contiguous
// bucket slices -> stays in one XCD's L2.
__global__ void hist_kernel(const int* __restrict__ src, const int* __restrict__ dst,
                            int* __restrict__ off2) {
  const int r = blockIdx.x & (NRANGE - 1);
  const int slice = blockIdx.x >> 3;
  const int nslices = gridDim.x >> 3;
  const int lo = r * (N_NODES / NRANGE);
  const int hi = lo + (N_NODES / NRANGE);
  const int per = (N_EDGES + nslices - 1) / nslices;
  const int beg = slice * per;
  int end = beg + per; if (end > N_EDGES) end = N_EDGES;
  for (int e = beg + threadIdx.x; e < end; e += blockDim.x) {
    int s = __builtin_nontemporal_load(src + e);
    if (s >= lo && s < hi) {
      int d = __builtin_nontemporal_load(dst + e);
      atomicAdd(&off2[(s >> BSHIFT) * N_NODES + d + 1], 1);
    }
  }
}

// 3-phase parallel scan over off2[0..NOFF2], inclusive, in place.
__launch_bounds__(SCAN_BS)
__global__ void scanA_kernel(const int* __restrict__ off2, int* __restrict__ psum) {
  __shared__ int s[SCAN_BS];
  int b = blockIdx.x, t = threadIdx.x;
  int idx = b * SCAN_BS + t;
  s[t] = (idx < M2) ? off2[idx] : 0;
  __syncthreads();
  for (int d = SCAN_BS / 2; d > 0; d >>= 1) {
    if (t < d) s[t] += s[t + d];
    __syncthreads();
  }
  if (t == 0) psum[b] = s[0];
}

__launch_bounds__(SCANB_T)
__global__ void scanB_kernel(int* __restrict__ psum) {
  __shared__ int s[SCANB_T];
  int t = threadIdx.x;
  int base = t * SCANB_CH;
  int v[SCANB_CH];
  int sum = 0;
#pragma unroll
  for (int k = 0; k < SCANB_CH; ++k) {
    int i = base + k;
    v[k] = (i < SCAN_NBLK2) ? psum[i] : 0;
    sum += v[k];
  }
  s[t] = sum;
  __syncthreads();
  for (int d = 1; d < SCANB_T; d <<= 1) {
    int x = (t >= d) ? s[t - d] : 0;
    __syncthreads();
    s[t] += x;
    __syncthreads();
  }
  int run = (t == 0) ? 0 : s[t - 1];
#pragma unroll
  for (int k = 0; k < SCANB_CH; ++k) {
    int i = base + k;
    if (i < SCAN_NBLK2) { psum[i] = run; run += v[k]; }
  }
}

__launch_bounds__(SCAN_BS)
__global__ void scanC_kernel(int* __restrict__ off2, int* __restrict__ cursor2,
                             const int* __restrict__ psum) {
  __shared__ int s[SCAN_BS];
  int b = blockIdx.x, t = threadIdx.x;
  int idx = b * SCAN_BS + t;
  s[t] = (idx < M2) ? off2[idx] : 0;
  __syncthreads();
  for (int d = 1; d < SCAN_BS; d <<= 1) {
    int v = (t >= d) ? s[t - d] : 0;
    __syncthreads();
    s[t] += v;
    __syncthreads();
  }
  int run = s[t] + psum[b];
  if (idx < M2) {
    off2[idx] = run;
    if (idx < NOFF2) cursor2[idx] = run;
  }
}

// fill: src-range partitioned; edge payload packs row-tag (dst%13) into bits 17..20.
__global__ void fill_kernel(const int* __restrict__ src, const int* __restrict__ dst,
                            const float* __restrict__ w, int* __restrict__ cursor2,
                            int2* __restrict__ edges) {
  const int r = blockIdx.x & (NRANGE - 1);
  const int slice = blockIdx.x >> 3;
  const int nslices = gridDim.x >> 3;
  const int lo = r * (N_NODES / NRANGE);
  const int hi = lo + (N_NODES / NRANGE);
  const int per = (N_EDGES + nslices - 1) / nslices;
  const int beg = slice * per;
  int end = beg + per; if (end > N_EDGES) end = N_EDGES;
  for (int e = beg + threadIdx.x; e < end; e += blockDim.x) {
    int s = __builtin_nontemporal_load(src + e);
    if (s >= lo && s < hi) {
      int d = __builtin_nontemporal_load(dst + e);
      float wv = __builtin_nontemporal_load(w + e);
      int p = atomicAdd(&cursor2[(s >> BSHIFT) * N_NODES + d], 1);
      int tag = d % RPW;                       // row index within owning wave
      edges[p] = make_int2((tag << 17) | s, __float_as_int(wv));
    }
  }
}

// ---------------- fc1 ----------------
__launch_bounds__(256)
__global__ void fc1_kernel(const float* __restrict__ F, const float* __restrict__ W1,
                           const float* __restrict__ bias1, const float* __restrict__ noise,
                           float* __restrict__ x, float* __restrict__ nn0) {
  __shared__ float Fs[KT][132];
  __shared__ float Ws[KT][64];
  __shared__ float red[64];
  const int t = threadIdx.x;
  const int tx = t & 15;
  const int ty = t >> 4;
  const int c0 = tx * 4;
  const int n0 = ty * 8;
  const int nodeBase = blockIdx.x * 128;
  const int fk = (t & 7) * 4;
  const int fn = t >> 3;
  const int wr = t >> 3;
  const int wc = (t & 7) * 8;

  float4 fr[4];
  float4 w0r, w1r;
  {
#pragma unroll
    for (int p = 0; p < 4; ++p) {
      int n = nodeBase + fn + 32 * p;
      float4 v = make_float4(0.f, 0.f, 0.f, 0.f);
      if (n < N_NODES && fk + 3 < IN_FEATS) v = *(const float4*)(F + (size_t)n * IN_FEATS + fk);
      fr[p] = v;
    }
    float4 a = make_float4(0.f, 0.f, 0.f, 0.f), b = a;
    if (wr < IN_FEATS) {
      a = *(const float4*)(W1 + (size_t)wr * HID + wc);
      b = *(const float4*)(W1 + (size_t)wr * HID + wc + 4);
    }
    w0r = a; w1r = b;
  }

  float acc[8][4];
#pragma unroll
  for (int i = 0; i < 8; ++i)
#pragma unroll
    for (int j = 0; j < 4; ++j) acc[i][j] = 0.f;

  const int NTILE = (IN_FEATS + KT - 1) / KT;
  for (int tile = 0; tile < NTILE; ++tile) {
    __syncthreads();
#pragma unroll
    for (int p = 0; p < 4; ++p) {
      Fs[fk + 0][fn + 32 * p] = fr[p].x;
      Fs[fk + 1][fn + 32 * p] = fr[p].y;
      Fs[fk + 2][fn + 32 * p] = fr[p].z;
      Fs[fk + 3][fn + 32 * p] = fr[p].w;
    }
    *(float4*)&Ws[wr][wc] = w0r;
    *(float4*)&Ws[wr][wc + 4] = w1r;
    __syncthreads();
    if (tile + 1 < NTILE) {
      const int kb = (tile + 1) * KT;
#pragma unroll
      for (int p = 0; p < 4; ++p) {
        int n = nodeBase + fn + 32 * p;
        int k = kb + fk;
        float4 v = make_float4(0.f, 0.f, 0.f, 0.f);
        if (n < N_NODES && k + 3 < IN_FEATS) v = *(const float4*)(F + (size_t)n * IN_FEATS + k);
        fr[p] = v;
      }
      int k = kb + wr;
      float4 a = make_float4(0.f, 0.f, 0.f, 0.f), b = a;
      if (k < IN_FEATS) {
        a = *(const float4*)(W1 + (size_t)k * HID + wc);
        b = *(const float4*)(W1 + (size_t)k * HID + wc + 4);
      }
      w0r = a; w1r = b;
    }
#pragma unroll 8
    for (int kk = 0; kk < KT; ++kk) {
      float4 fa = *(float4*)&Fs[kk][n0];
      float4 fb = *(float4*)&Fs[kk][n0 + 4];
      float4 wv = *(float4*)&Ws[kk][c0];
      acc[0][0] = fmaf(fa.x, wv.x, acc[0][0]); acc[0][1] = fmaf(fa.x, wv.y, acc[0][1]);
      acc[0][2] = fmaf(fa.x, wv.z, acc[0][2]); acc[0][3] = fmaf(fa.x, wv.w, acc[0][3]);
      acc[1][0] = fmaf(fa.y, wv.x, acc[1][0]); acc[1][1] = fmaf(fa.y, wv.y, acc[1][1]);
      acc[1][2] = fmaf(fa.y, wv.z, acc[1][2]); acc[1][3] = fmaf(fa.y, wv.w, acc[1][3]);
      acc[2][0] = fmaf(fa.z, wv.x, acc[2][0]); acc[2][1] = fmaf(fa.z, wv.y, acc[2][1]);
      acc[2][2] = fmaf(fa.z, wv.z, acc[2][2]); acc[2][3] = fmaf(fa.z, wv.w, acc[2][3]);
      acc[3][0] = fmaf(fa.w, wv.x, acc[3][0]); acc[3][1] = fmaf(fa.w, wv.y, acc[3][1]);
      acc[3][2] = fmaf(fa.w, wv.z, acc[3][2]); acc[3][3] = fmaf(fa.w, wv.w, acc[3][3]);
      acc[4][0] = fmaf(fb.x, wv.x, acc[4][0]); acc[4][1] = fmaf(fb.x, wv.y, acc[4][1]);
      acc[4][2] = fmaf(fb.x, wv.z, acc[4][2]); acc[4][3] = fmaf(fb.x, wv.w, acc[4][3]);
      acc[5][0] = fmaf(fb.y, wv.x, acc[5][0]); acc[5][1] = fmaf(fb.y, wv.y, acc[5][1]);
      acc[5][2] = fmaf(fb.y, wv.z, acc[5][2]); acc[5][3] = fmaf(fb.y, wv.w, acc[5][3]);
      acc[6][0] = fmaf(fb.z, wv.x, acc[6][0]); acc[6][1] = fmaf(fb.z, wv.y, acc[6][1]);
      acc[6][2] = fmaf(fb.z, wv.z, acc[6][2]); acc[6][3] = fmaf(fb.z, wv.w, acc[6][3]);
      acc[7][0] = fmaf(fb.w, wv.x, acc[7][0]); acc[7][1] = fmaf(fb.w, wv.y, acc[7][1]);
      acc[7][2] = fmaf(fb.w, wv.z, acc[7][2]); acc[7][3] = fmaf(fb.w, wv.w, acc[7][3]);
    }
  }

  float4 bb = *(const float4*)(bias1 + c0);
  float np0 = 0.f, np1 = 0.f, np2 = 0.f, np3 = 0.f;
#pragma unroll
  for (int i = 0; i < 8; ++i) {
    int n = nodeBase + n0 + i;
    if (n < N_NODES) {
      float4 nz = *(const float4*)(noise + (size_t)n * HID + c0);
      float v0 = fmaxf(acc[i][0] + bb.x, 0.f) + nz.x * 1e-5f;
      float v1 = fmaxf(acc[i][1] + bb.y, 0.f) + nz.y * 1e-5f;
      float v2 = fmaxf(acc[i][2] + bb.z, 0.f) + nz.z * 1e-5f;
      float v3 = fmaxf(acc[i][3] + bb.w, 0.f) + nz.w * 1e-5f;
      *(float4*)(x + (size_t)n * HID + c0) = make_float4(v0, v1, v2, v3);
      np0 = fmaf(v0, v0, np0); np1 = fmaf(v1, v1, np1);
      np2 = fmaf(v2, v2, np2); np3 = fmaf(v3, v3, np3);
    }
  }
  if (t < 64) red[t] = 0.f;
  __syncthreads();
  atomicAdd(&red[c0 + 0], np0); atomicAdd(&red[c0 + 1], np1);
  atomicAdd(&red[c0 + 2], np2); atomicAdd(&red[c0 + 3], np3);
  __syncthreads();
  if (t < 64) atomicAdd(&nn0[t], red[t]);
}

// ---------------- SpMM: bucket-major sweep, LDS row accumulators ----------------
// Wave w owns 13 consecutive dst rows [13w, 13w+13); edges sorted by (bucket,dst)
// give ONE contiguous range per (wave,bucket). Row routing is branch-free: the
// 4-bit row tag (edge bits 17..20) indexes a per-wave LDS accumulator block and
// each edge issues a single fire-and-forget ds_add (atomicAdd on own lane slot,
// conflict-free 2-lanes/bank). Inner loop has zero control flow -> compiler can
// software-pipeline edge-load -> gather -> ds_add across iterations.
__launch_bounds__(256, 8)
__global__ void spmm_kernel(const int2* __restrict__ edges, const int* __restrict__ off2,
                            const float* __restrict__ lastr, const float* __restrict__ secondr,
                            const float* __restrict__ nn_l,
                            float* __restrict__ h, float* __restrict__ dslot) {
  __shared__ float acc_s[4 * RPW * 64];   // 13312 B: [wave][tag][lane]
  __shared__ float red[128];
  const int t = threadIdx.x;
  const int lane = t & 63;
  const int wid = t >> 6;
  float* __restrict__ myacc = &acc_s[(wid * RPW) * 64 + lane];
#pragma unroll
  for (int d = 0; d < RPW; ++d) myacc[d * 64] = 0.f;
  if (t < 128) red[t] = 0.f;
  __syncthreads();

  const float sig = 1.f / fmaxf(sqrtf(nn_l[lane]), 1e-8f);
  const int w = blockIdx.x * 4 + wid;   // 0..8191
  const int rlo = w * RPW;
  const unsigned long long* __restrict__ eraw = (const unsigned long long*)edges;
  const float* __restrict__ lrl = lastr + lane;

  if (rlo < N_NODES) {
    const int rhi = (rlo + RPW < N_NODES) ? rlo + RPW : N_NODES;
    for (int b = 0; b < NBKT; ++b) {
      const int kb = b * N_NODES;
      const int beg = __builtin_amdgcn_readfirstlane(off2[kb + rlo]);
      const int end = __builtin_amdgcn_readfirstlane(off2[kb + rhi]);
      int j = beg;
      for (; j + 4 <= end; j += 4) {
        unsigned long long e0 = __builtin_nontemporal_load(eraw + j + 0);
        unsigned long long e1 = __builtin_nontemporal_load(eraw + j + 1);
        unsigned long long e2 = __builtin_nontemporal_load(eraw + j + 2);
        unsigned long long e3 = __builtin_nontemporal_load(eraw + j + 3);
        int l0 = (int)e0, l1 = (int)e1, l2 = (int)e2, l3 = (int)e3;
        float g0 = lrl[(size_t)((l0 & 0x1FFFF) * HID)];
        float g1 = lrl[(size_t)((l1 & 0x1FFFF) * HID)];
        float g2 = lrl[(size_t)((l2 & 0x1FFFF) * HID)];
        float g3 = lrl[(size_t)((l3 & 0x1FFFF) * HID)];
        atomicAdd(&myacc[(l0 >> 17) * 64], g0 * __int_as_float((int)(e0 >> 32)));
        atomicAdd(&myacc[(l1 >> 17) * 64], g1 * __int_as_float((int)(e1 >> 32)));
        atomicAdd(&myacc[(l2 >> 17) * 64], g2 * __int_as_float((int)(e2 >> 32)));
        atomicAdd(&myacc[(l3 >> 17) * 64], g3 * __int_as_float((int)(e3 >> 32)));
      }
      for (; j < end; ++j) {
        unsigned long long e = __builtin_nontemporal_load(eraw + j);
        int l0 = (int)e;
        float g = lrl[(size_t)((l0 & 0x1FFFF) * HID)];
        atomicAdd(&myacc[(l0 >> 17) * 64], g * __int_as_float((int)(e >> 32)));
      }
    }
  }

  float d1 = 0.f, d2 = 0.f;
#pragma unroll
  for (int d = 0; d < RPW; ++d) {
    const int n = rlo + d;
    if (n < N_NODES) {
      size_t o = (size_t)n * HID + lane;
      float a = myacc[d * 64] * sig;
      float l = lastr[o];
      float s = __builtin_nontemporal_load(secondr + o);
      __builtin_nontemporal_store(a, h + o);
      d1 = fmaf(a, l, d1);
      d2 = fmaf(a, s, d2);
    }
  }
  atomicAdd(&red[lane], d1);
  atomicAdd(&red[64 + lane], d2);
  __syncthreads();
  if (t < 128) atomicAdd(&dslot[t], red[t]);
}

// ---------------- passB ----------------
__launch_bounds__(256)
__global__ void passB_kernel(float4* __restrict__ h4, const float4* __restrict__ l4,
                             const float4* __restrict__ s4, float* __restrict__ dcur,
                             const float* __restrict__ nn_l, const float* __restrict__ nn_s,
                             const float* __restrict__ alpha, int prevcol, int accum,
                             float4* __restrict__ rst4) {
  __shared__ float red[64];
  int t = threadIdx.x;
  int q = t & 15;
  int c0 = q * 4;
  float4 NL = ((const float4*)nn_l)[q];
  float4 NS = ((const float4*)nn_s)[q];
  float4 D1 = ((const float4*)dcur)[q];
  float4 D2 = ((const float4*)(dcur + 64))[q];
  float4 sigl, sigs;
  sigl.x = 1.f / fmaxf(sqrtf(NL.x), 1e-8f); sigl.y = 1.f / fmaxf(sqrtf(NL.y), 1e-8f);
  sigl.z = 1.f / fmaxf(sqrtf(NL.z), 1e-8f); sigl.w = 1.f / fmaxf(sqrtf(NL.w), 1e-8f);
  sigs.x = 1.f / fmaxf(sqrtf(NS.x), 1e-8f); sigs.y = 1.f / fmaxf(sqrtf(NS.y), 1e-8f);
  sigs.z = 1.f / fmaxf(sqrtf(NS.z), 1e-8f); sigs.w = 1.f / fmaxf(sqrtf(NS.w), 1e-8f);
  float4 C1, C2, AL;
  C1.x = sigl.x * sigl.x * D1.x; C1.y = sigl.y * sigl.y * D1.y;
  C1.z = sigl.z * sigl.z * D1.z; C1.w = sigl.w * sigl.w * D1.w;
  C2.x = sigs.x * sigs.x * D2.x; C2.y = sigs.y * sigs.y * D2.y;
  C2.z = sigs.z * sigs.z * D2.z; C2.w = sigs.w * sigs.w * D2.w;
  AL.x = alpha[(size_t)(c0 + 0) * (KHOPS + 1) + prevcol] * sigl.x;
  AL.y = alpha[(size_t)(c0 + 1) * (KHOPS + 1) + prevcol] * sigl.y;
  AL.z = alpha[(size_t)(c0 + 2) * (KHOPS + 1) + prevcol] * sigl.z;
  AL.w = alpha[(size_t)(c0 + 3) * (KHOPS + 1) + prevcol] * sigl.w;
  float nx = 0.f, ny = 0.f, nz = 0.f, nw = 0.f;
  int row0 = blockIdx.x * 16 + (t >> 4);
  int rstride = gridDim.x * 16;
  for (int n = row0; n < N_NODES; n += rstride) {
    size_t idx = (size_t)n * 16 + q;
    float4 h = h4[idx];
    float4 l = l4[idx];
    float4 s = s4[idx];
    h.x -= C1.x * l.x + C2.x * s.x;
    h.y -= C1.y * l.y + C2.y * s.y;
    h.z -= C1.z * l.z + C2.z * s.z;
    h.w -= C1.w * l.w + C2.w * s.w;
    h4[idx] = h;
    nx = fmaf(h.x, h.x, nx); ny = fmaf(h.y, h.y, ny);
    nz = fmaf(h.z, h.z, nz); nw = fmaf(h.w, h.w, nw);
    float4 r;
    if (accum) {
      r = rst4[idx];
      r.x = fmaf(AL.x, l.x, r.x); r.y = fmaf(AL.y, l.y, r.y);
      r.z = fmaf(AL.z, l.z, r.z); r.w = fmaf(AL.w, l.w, r.w);
    } else {
      r.x = AL.x * l.x; r.y = AL.y * l.y; r.z = AL.z * l.z; r.w = AL.w * l.w;
    }
    rst4[idx] = r;
  }
  if (t < 64) red[t] = 0.f;
  __syncthreads();
  atomicAdd(&red[c0 + 0], nx); atomicAdd(&red[c0 + 1], ny);
  atomicAdd(&red[c0 + 2], nz); atomicAdd(&red[c0 + 3], nw);
  __syncthreads();
  if (t < 64) atomicAdd(&dcur[128 + t], red[t]);
}

// ---------------- fc2 ----------------
__launch_bounds__(256)
__global__ void gemm2_kernel(const float* __restrict__ rst, const float* __restrict__ hK,
                             const float* __restrict__ nnK, const float* __restrict__ alpha,
                             const float* __restrict__ W2, const float* __restrict__ bias2,
                             float* __restrict__ out) {
  __shared__ float W2s[HID * CLS];
  __shared__ float R[64][65];
  __shared__ float coef[64];
  int t = threadIdx.x;
  if (t < 64) coef[t] = alpha[(size_t)t * (KHOPS + 1) + KHOPS] / fmaxf(sqrtf(nnK[t]), 1e-8f);
  for (int i = t; i < HID * CLS; i += 256) W2s[i] = W2[i];
  int nodeBase = blockIdx.x * 64;
  __syncthreads();
  for (int i = t; i < 64 * 16; i += 256) {
    int r = i >> 4, c4 = (i & 15) * 4;
    int n = nodeBase + r;
    if (n < N_NODES) {
      float4 rv = *(const float4*)(rst + (size_t)n * HID + c4);
      float4 hv = *(const float4*)(hK + (size_t)n * HID + c4);
      R[r][c4 + 0] = rv.x + coef[c4 + 0] * hv.x;
      R[r][c4 + 1] = rv.y + coef[c4 + 1] * hv.y;
      R[r][c4 + 2] = rv.z + coef[c4 + 2] * hv.z;
      R[r][c4 + 3] = rv.w + coef[c4 + 3] * hv.w;
    } else {
      R[r][c4 + 0] = 0.f; R[r][c4 + 1] = 0.f; R[r][c4 + 2] = 0.f; R[r][c4 + 3] = 0.f;
    }
  }
  __syncthreads();
  int node = t >> 2;
  int cls0 = (t & 3) * 10;
  float o[10];
#pragma unroll
  for (int j = 0; j < 10; ++j) o[j] = bias2[cls0 + j];
#pragma unroll 4
  for (int k = 0; k < HID; ++k) {
    float rv = R[node][k];
    const float* wrow = &W2s[k * CLS + cls0];
#pragma unroll
    for (int j = 0; j < 10; ++j) o[j] = fmaf(rv, wrow[j], o[j]);
  }
  int n = nodeBase + node;
  if (n < N_NODES) {
#pragma unroll
    for (int j = 0; j < 10; ++j) out[(size_t)n * CLS + cls0 + j] = o[j];
  }
}

extern "C" void kernel_launch(void* const* d_in, const int* in_sizes, int n_in,
                              void* d_out, int out_size, void* d_ws, size_t ws_size,
                              hipStream_t stream) {
  (void)in_sizes; (void)n_in; (void)out_size;
  const float* features  = (const float*)d_in[0];
  const float* noise     = (const float*)d_in[1];
  const float* norm_A    = (const float*)d_in[2];
  const float* W1        = (const float*)d_in[3];
  const float* b1        = (const float*)d_in[4];
  const float* W2        = (const float*)d_in[5];
  const float* b2        = (const float*)d_in[6];
  const float* alpha     = (const float*)d_in[7];
  const int*   edge_index= (const int*)d_in[8];
  float* out = (float*)d_out;

  char* ws = (char*)d_ws;
  const size_t NB = (size_t)N_NODES * HID * sizeof(float);   // 25,600,000
  const size_t OFF2_BYTES = 5200128;                          // (NOFF2+1)*4 padded
  const size_t DOTS_BYTES = (size_t)12 * 192 * 4;             // 9216
  float* hA    = (float*)(ws);
  float* hC    = (float*)(ws + NB);
  float* rst   = (float*)(ws + 2 * NB);
  int2*  edges = (int2*)(ws + 3 * NB);
  char*  zbase = ws + 4 * NB;
  float* hB    = (float*)(zbase);                             // zeroed -> initial "second"
  int*   off2  = (int*)(zbase + NB);                          // zeroed -> hist bins
  float* dots  = (float*)(zbase + NB + OFF2_BYTES);           // zeroed
  const size_t zspan = NB + OFF2_BYTES + DOTS_BYTES;          // mult of 16
  int*   psum  = (int*)(zbase + zspan);                       // SCAN_NBLK2 ints
  // cursor2 overlays rst: rst is first written by passB(i=1) with accum=0 (pure
  // overwrite), which happens strictly after fill completes on this stream.
  int*   cursor2 = (int*)rst;
  const size_t total = 4 * NB + zspan + 20480;
  if (ws_size < total) return;

  zero_kernel<<<4096, 256, 0, stream>>>((float4*)zbase, zspan / 16);
  hist_kernel<<<2048, 256, 0, stream>>>(edge_index, edge_index + N_EDGES, off2);
  scanA_kernel<<<SCAN_NBLK2, SCAN_BS, 0, stream>>>(off2, psum);
  scanB_kernel<<<1, SCANB_T, 0, stream>>>(psum);
  scanC_kernel<<<SCAN_NBLK2, SCAN_BS, 0, stream>>>(off2, cursor2, psum);
  fill_kernel<<<2048, 256, 0, stream>>>(edge_index, edge_index + N_EDGES, norm_A, cursor2, edges);
  fc1_kernel<<<(N_NODES + 127) / 128, 256, 0, stream>>>(features, W1, b1, noise, hA,
                                                        dots + 1 * 192 + 128);
  float* second = hB; float* last = hA; float* cur = hC;
  for (int i = 1; i <= KHOPS; ++i) {
    float* dc = dots + (size_t)(i + 1) * 192;
    float* nl = dots + (size_t)(i)     * 192 + 128;
    float* ns = dots + (size_t)(i - 1) * 192 + 128;
    spmm_kernel<<<2048, 256, 0, stream>>>(edges, off2, last, second, nl, cur, dc);
    passB_kernel<<<1024, 256, 0, stream>>>((float4*)cur, (const float4*)last,
                                           (const float4*)second, dc, nl, ns,
                                           alpha, i - 1, (i > 1) ? 1 : 0, (float4*)rst);
    float* tmp = second; second = last; last = cur; cur = tmp;
  }
  gemm2_kernel<<<(N_NODES + 63) / 64, 256, 0, stream>>>(rst, last,
                                                        dots + (size_t)(KHOPS + 1) * 192 + 128,
                                                        alpha, W2, b2, out);
}

// Round 5
// 2571.494 us; speedup vs baseline: 4.7828x; 4.7828x over previous
//
#include <hip/hip_runtime.h>
#include <stdint.h>

#define N_NODES 100000
#define N_EDGES 3200000
#define IN_FEATS 500
#define HID 64
#define CLS 40
#define KHOPS 10
#define KT 32
#define NRANGE 8
#define NBKT 13          // src buckets: src>>13, 8192 nodes = 2MB of lastr per bucket
#define BSHIFT 13
#define RPW 13           // dst rows per wave (8192 waves x 13 >= 100000)
#define RSPLIT 7         // rows 0..6 -> chain A, rows 7..12 -> chain B
#define NOFF2 (N_NODES * NBKT)       // 1,300,000 (bucket,dst) bins
#define M2 (NOFF2 + 1)               // scan length
#define SCAN_BS 256
#define SCAN_NBLK2 ((M2 + SCAN_BS - 1) / SCAN_BS)   // 5079
#define SCANB_T 1024
#define SCANB_CH ((SCAN_NBLK2 + SCANB_T - 1) / SCANB_T)  // 5

// ---------------- generic zero ----------------
__global__ void zero_kernel(float4* __restrict__ p, size_t n4) {
  size_t i = (size_t)blockIdx.x * blockDim.x + threadIdx.x;
  size_t stride = (size_t)gridDim.x * blockDim.x;
  float4 z = make_float4(0.f, 0.f, 0.f, 0.f);
  for (; i < n4; i += stride) p[i] = z;
}

// ---------------- CSR build over (bucket, dst) keys ----------------
__global__ void hist_kernel(const int* __restrict__ src, const int* __restrict__ dst,
                            int* __restrict__ off2) {
  const int r = blockIdx.x & (NRANGE - 1);
  const int slice = blockIdx.x >> 3;
  const int nslices = gridDim.x >> 3;
  const int lo = r * (N_NODES / NRANGE);
  const int hi = lo + (N_NODES / NRANGE);
  const int per = (N_EDGES + nslices - 1) / nslices;
  const int beg = slice * per;
  int end = beg + per; if (end > N_EDGES) end = N_EDGES;
  for (int e = beg + threadIdx.x; e < end; e += blockDim.x) {
    int s = __builtin_nontemporal_load(src + e);
    if (s >= lo && s < hi) {
      int d = __builtin_nontemporal_load(dst + e);
      atomicAdd(&off2[(s >> BSHIFT) * N_NODES + d + 1], 1);
    }
  }
}

__launch_bounds__(SCAN_BS)
__global__ void scanA_kernel(const int* __restrict__ off2, int* __restrict__ psum) {
  __shared__ int s[SCAN_BS];
  int b = blockIdx.x, t = threadIdx.x;
  int idx = b * SCAN_BS + t;
  s[t] = (idx < M2) ? off2[idx] : 0;
  __syncthreads();
  for (int d = SCAN_BS / 2; d > 0; d >>= 1) {
    if (t < d) s[t] += s[t + d];
    __syncthreads();
  }
  if (t == 0) psum[b] = s[0];
}

__launch_bounds__(SCANB_T)
__global__ void scanB_kernel(int* __restrict__ psum) {
  __shared__ int s[SCANB_T];
  int t = threadIdx.x;
  int base = t * SCANB_CH;
  int v[SCANB_CH];
  int sum = 0;
#pragma unroll
  for (int k = 0; k < SCANB_CH; ++k) {
    int i = base + k;
    v[k] = (i < SCAN_NBLK2) ? psum[i] : 0;
    sum += v[k];
  }
  s[t] = sum;
  __syncthreads();
  for (int d = 1; d < SCANB_T; d <<= 1) {
    int x = (t >= d) ? s[t - d] : 0;
    __syncthreads();
    s[t] += x;
    __syncthreads();
  }
  int run = (t == 0) ? 0 : s[t - 1];
#pragma unroll
  for (int k = 0; k < SCANB_CH; ++k) {
    int i = base + k;
    if (i < SCAN_NBLK2) { psum[i] = run; run += v[k]; }
  }
}

__launch_bounds__(SCAN_BS)
__global__ void scanC_kernel(int* __restrict__ off2, int* __restrict__ cursor2,
                             const int* __restrict__ psum) {
  __shared__ int s[SCAN_BS];
  int b = blockIdx.x, t = threadIdx.x;
  int idx = b * SCAN_BS + t;
  s[t] = (idx < M2) ? off2[idx] : 0;
  __syncthreads();
  for (int d = 1; d < SCAN_BS; d <<= 1) {
    int v = (t >= d) ? s[t - d] : 0;
    __syncthreads();
    s[t] += v;
    __syncthreads();
  }
  int run = s[t] + psum[b];
  if (idx < M2) {
    off2[idx] = run;
    if (idx < NOFF2) cursor2[idx] = run;
  }
}

// fill: src-range partitioned; edge payload packs row-tag (dst%13) into bits 17..20.
__global__ void fill_kernel(const int* __restrict__ src, const int* __restrict__ dst,
                            const float* __restrict__ w, int* __restrict__ cursor2,
                            int2* __restrict__ edges) {
  const int r = blockIdx.x & (NRANGE - 1);
  const int slice = blockIdx.x >> 3;
  const int nslices = gridDim.x >> 3;
  const int lo = r * (N_NODES / NRANGE);
  const int hi = lo + (N_NODES / NRANGE);
  const int per = (N_EDGES + nslices - 1) / nslices;
  const int beg = slice * per;
  int end = beg + per; if (end > N_EDGES) end = N_EDGES;
  for (int e = beg + threadIdx.x; e < end; e += blockDim.x) {
    int s = __builtin_nontemporal_load(src + e);
    if (s >= lo && s < hi) {
      int d = __builtin_nontemporal_load(dst + e);
      float wv = __builtin_nontemporal_load(w + e);
      int p = atomicAdd(&cursor2[(s >> BSHIFT) * N_NODES + d], 1);
      int tag = d % RPW;                       // row index within owning wave
      edges[p] = make_int2((tag << 17) | s, __float_as_int(wv));
    }
  }
}

// ---------------- fc1 ----------------
__launch_bounds__(256)
__global__ void fc1_kernel(const float* __restrict__ F, const float* __restrict__ W1,
                           const float* __restrict__ bias1, const float* __restrict__ noise,
                           float* __restrict__ x, float* __restrict__ nn0) {
  __shared__ float Fs[KT][132];
  __shared__ float Ws[KT][64];
  __shared__ float red[64];
  const int t = threadIdx.x;
  const int tx = t & 15;
  const int ty = t >> 4;
  const int c0 = tx * 4;
  const int n0 = ty * 8;
  const int nodeBase = blockIdx.x * 128;
  const int fk = (t & 7) * 4;
  const int fn = t >> 3;
  const int wr = t >> 3;
  const int wc = (t & 7) * 8;

  float4 fr[4];
  float4 w0r, w1r;
  {
#pragma unroll
    for (int p = 0; p < 4; ++p) {
      int n = nodeBase + fn + 32 * p;
      float4 v = make_float4(0.f, 0.f, 0.f, 0.f);
      if (n < N_NODES && fk + 3 < IN_FEATS) v = *(const float4*)(F + (size_t)n * IN_FEATS + fk);
      fr[p] = v;
    }
    float4 a = make_float4(0.f, 0.f, 0.f, 0.f), b = a;
    if (wr < IN_FEATS) {
      a = *(const float4*)(W1 + (size_t)wr * HID + wc);
      b = *(const float4*)(W1 + (size_t)wr * HID + wc + 4);
    }
    w0r = a; w1r = b;
  }

  float acc[8][4];
#pragma unroll
  for (int i = 0; i < 8; ++i)
#pragma unroll
    for (int j = 0; j < 4; ++j) acc[i][j] = 0.f;

  const int NTILE = (IN_FEATS + KT - 1) / KT;
  for (int tile = 0; tile < NTILE; ++tile) {
    __syncthreads();
#pragma unroll
    for (int p = 0; p < 4; ++p) {
      Fs[fk + 0][fn + 32 * p] = fr[p].x;
      Fs[fk + 1][fn + 32 * p] = fr[p].y;
      Fs[fk + 2][fn + 32 * p] = fr[p].z;
      Fs[fk + 3][fn + 32 * p] = fr[p].w;
    }
    *(float4*)&Ws[wr][wc] = w0r;
    *(float4*)&Ws[wr][wc + 4] = w1r;
    __syncthreads();
    if (tile + 1 < NTILE) {
      const int kb = (tile + 1) * KT;
#pragma unroll
      for (int p = 0; p < 4; ++p) {
        int n = nodeBase + fn + 32 * p;
        int k = kb + fk;
        float4 v = make_float4(0.f, 0.f, 0.f, 0.f);
        if (n < N_NODES && k + 3 < IN_FEATS) v = *(const float4*)(F + (size_t)n * IN_FEATS + k);
        fr[p] = v;
      }
      int k = kb + wr;
      float4 a = make_float4(0.f, 0.f, 0.f, 0.f), b = a;
      if (k < IN_FEATS) {
        a = *(const float4*)(W1 + (size_t)k * HID + wc);
        b = *(const float4*)(W1 + (size_t)k * HID + wc + 4);
      }
      w0r = a; w1r = b;
    }
#pragma unroll 8
    for (int kk = 0; kk < KT; ++kk) {
      float4 fa = *(float4*)&Fs[kk][n0];
      float4 fb = *(float4*)&Fs[kk][n0 + 4];
      float4 wv = *(float4*)&Ws[kk][c0];
      acc[0][0] = fmaf(fa.x, wv.x, acc[0][0]); acc[0][1] = fmaf(fa.x, wv.y, acc[0][1]);
      acc[0][2] = fmaf(fa.x, wv.z, acc[0][2]); acc[0][3] = fmaf(fa.x, wv.w, acc[0][3]);
      acc[1][0] = fmaf(fa.y, wv.x, acc[1][0]); acc[1][1] = fmaf(fa.y, wv.y, acc[1][1]);
      acc[1][2] = fmaf(fa.y, wv.z, acc[1][2]); acc[1][3] = fmaf(fa.y, wv.w, acc[1][3]);
      acc[2][0] = fmaf(fa.z, wv.x, acc[2][0]); acc[2][1] = fmaf(fa.z, wv.y, acc[2][1]);
      acc[2][2] = fmaf(fa.z, wv.z, acc[2][2]); acc[2][3] = fmaf(fa.z, wv.w, acc[2][3]);
      acc[3][0] = fmaf(fa.w, wv.x, acc[3][0]); acc[3][1] = fmaf(fa.w, wv.y, acc[3][1]);
      acc[3][2] = fmaf(fa.w, wv.z, acc[3][2]); acc[3][3] = fmaf(fa.w, wv.w, acc[3][3]);
      acc[4][0] = fmaf(fb.x, wv.x, acc[4][0]); acc[4][1] = fmaf(fb.x, wv.y, acc[4][1]);
      acc[4][2] = fmaf(fb.x, wv.z, acc[4][2]); acc[4][3] = fmaf(fb.x, wv.w, acc[4][3]);
      acc[5][0] = fmaf(fb.y, wv.x, acc[5][0]); acc[5][1] = fmaf(fb.y, wv.y, acc[5][1]);
      acc[5][2] = fmaf(fb.y, wv.z, acc[5][2]); acc[5][3] = fmaf(fb.y, wv.w, acc[5][3]);
      acc[6][0] = fmaf(fb.z, wv.x, acc[6][0]); acc[6][1] = fmaf(fb.z, wv.y, acc[6][1]);
      acc[6][2] = fmaf(fb.z, wv.z, acc[6][2]); acc[6][3] = fmaf(fb.z, wv.w, acc[6][3]);
      acc[7][0] = fmaf(fb.w, wv.x, acc[7][0]); acc[7][1] = fmaf(fb.w, wv.y, acc[7][1]);
      acc[7][2] = fmaf(fb.w, wv.z, acc[7][2]); acc[7][3] = fmaf(fb.w, wv.w, acc[7][3]);
    }
  }

  float4 bb = *(const float4*)(bias1 + c0);
  float np0 = 0.f, np1 = 0.f, np2 = 0.f, np3 = 0.f;
#pragma unroll
  for (int i = 0; i < 8; ++i) {
    int n = nodeBase + n0 + i;
    if (n < N_NODES) {
      float4 nz = *(const float4*)(noise + (size_t)n * HID + c0);
      float v0 = fmaxf(acc[i][0] + bb.x, 0.f) + nz.x * 1e-5f;
      float v1 = fmaxf(acc[i][1] + bb.y, 0.f) + nz.y * 1e-5f;
      float v2 = fmaxf(acc[i][2] + bb.z, 0.f) + nz.z * 1e-5f;
      float v3 = fmaxf(acc[i][3] + bb.w, 0.f) + nz.w * 1e-5f;
      *(float4*)(x + (size_t)n * HID + c0) = make_float4(v0, v1, v2, v3);
      np0 = fmaf(v0, v0, np0); np1 = fmaf(v1, v1, np1);
      np2 = fmaf(v2, v2, np2); np3 = fmaf(v3, v3, np3);
    }
  }
  if (t < 64) red[t] = 0.f;
  __syncthreads();
  atomicAdd(&red[c0 + 0], np0); atomicAdd(&red[c0 + 1], np1);
  atomicAdd(&red[c0 + 2], np2); atomicAdd(&red[c0 + 3], np3);
  __syncthreads();
  if (t < 64) atomicAdd(&nn0[t], red[t]);
}

// ---------------- SpMM: bucket-major sweep, TWO independent edge chains -------
// Wave w owns 13 consecutive dst rows [13w, 13w+13); edges sorted by (bucket,dst)
// give ONE contiguous range per (wave,bucket). The range splits at row rlo+7 into
// chain A (tags 0..6) and chain B (tags 7..12): two INDEPENDENT dependence chains
// interleaved 4-wide each -> 8 loads + 8 gathers in flight (2x MLP vs R3).
// Row routing stays the proven run-length + wave-uniform switch flush.
__launch_bounds__(256, 8)
__global__ void spmm_kernel(const int2* __restrict__ edges, const int* __restrict__ off2,
                            const float* __restrict__ lastr, const float* __restrict__ secondr,
                            const float* __restrict__ nn_l,
                            float* __restrict__ h, float* __restrict__ dslot) {
  __shared__ float red[128];
  const int t = threadIdx.x;
  const int lane = t & 63;
  const int wid = __builtin_amdgcn_readfirstlane(t >> 6);
  if (t < 128) red[t] = 0.f;
  __syncthreads();
  const float sig = 1.f / fmaxf(sqrtf(nn_l[lane]), 1e-8f);
  const int w = blockIdx.x * 4 + wid;   // 0..8191
  const int rlo = w * RPW;
  const unsigned long long* __restrict__ eraw = (const unsigned long long*)edges;
  const float* __restrict__ lrl = lastr + lane;

  float acc[RPW];
#pragma unroll
  for (int d = 0; d < RPW; ++d) acc[d] = 0.f;

#define FLUSH(CD, A) do { switch (CD) { \
    case 0: acc[0] += (A); break;  case 1: acc[1] += (A); break; \
    case 2: acc[2] += (A); break;  case 3: acc[3] += (A); break; \
    case 4: acc[4] += (A); break;  case 5: acc[5] += (A); break; \
    case 6: acc[6] += (A); break;  case 7: acc[7] += (A); break; \
    case 8: acc[8] += (A); break;  case 9: acc[9] += (A); break; \
    case 10: acc[10] += (A); break; case 11: acc[11] += (A); break; \
    default: acc[12] += (A); break; } } while (0)

#define STEP(E, G, CURD, A) do { \
    int lo_ = (int)(unsigned)((E) & 0xffffffffull); \
    int d_ = __builtin_amdgcn_readfirstlane(lo_ >> 17); \
    if (d_ != (CURD)) { FLUSH((CURD), (A)); (A) = 0.f; (CURD) = d_; } \
    float w_ = __int_as_float((int)(unsigned)((E) >> 32)); \
    (A) = fmaf(w_, (G), (A)); \
  } while (0)

  if (rlo < N_NODES) {
    const int rhi  = (rlo + RPW    < N_NODES) ? rlo + RPW    : N_NODES;
    const int rmid = (rlo + RSPLIT < N_NODES) ? rlo + RSPLIT : N_NODES;
    for (int b = 0; b < NBKT; ++b) {
      const int kb = b * N_NODES;
      int jA = __builtin_amdgcn_readfirstlane(off2[kb + rlo]);
      const int endA = __builtin_amdgcn_readfirstlane(off2[kb + rmid]);
      int jB = endA;
      const int endB = __builtin_amdgcn_readfirstlane(off2[kb + rhi]);
      int curdA = 0;      float aA = 0.f;
      int curdB = RSPLIT; float aB = 0.f;
      // interleaved dual-chain main loop: 8 loads + 8 gathers in flight
      while (jA + 4 <= endA && jB + 4 <= endB) {
        unsigned long long e0 = __builtin_nontemporal_load(eraw + jA + 0);
        unsigned long long e1 = __builtin_nontemporal_load(eraw + jA + 1);
        unsigned long long e2 = __builtin_nontemporal_load(eraw + jA + 2);
        unsigned long long e3 = __builtin_nontemporal_load(eraw + jA + 3);
        unsigned long long f0 = __builtin_nontemporal_load(eraw + jB + 0);
        unsigned long long f1 = __builtin_nontemporal_load(eraw + jB + 1);
        unsigned long long f2 = __builtin_nontemporal_load(eraw + jB + 2);
        unsigned long long f3 = __builtin_nontemporal_load(eraw + jB + 3);
        float g0 = lrl[(size_t)((((int)e0) & 0x1FFFF) * HID)];
        float g1 = lrl[(size_t)((((int)e1) & 0x1FFFF) * HID)];
        float g2 = lrl[(size_t)((((int)e2) & 0x1FFFF) * HID)];
        float g3 = lrl[(size_t)((((int)e3) & 0x1FFFF) * HID)];
        float q0 = lrl[(size_t)((((int)f0) & 0x1FFFF) * HID)];
        float q1 = lrl[(size_t)((((int)f1) & 0x1FFFF) * HID)];
        float q2 = lrl[(size_t)((((int)f2) & 0x1FFFF) * HID)];
        float q3 = lrl[(size_t)((((int)f3) & 0x1FFFF) * HID)];
        STEP(e0, g0, curdA, aA); STEP(e1, g1, curdA, aA);
        STEP(e2, g2, curdA, aA); STEP(e3, g3, curdA, aA);
        STEP(f0, q0, curdB, aB); STEP(f1, q1, curdB, aB);
        STEP(f2, q2, curdB, aB); STEP(f3, q3, curdB, aB);
        jA += 4; jB += 4;
      }
      // drain chain A
      for (; jA + 4 <= endA; jA += 4) {
        unsigned long long e0 = __builtin_nontemporal_load(eraw + jA + 0);
        unsigned long long e1 = __builtin_nontemporal_load(eraw + jA + 1);
        unsigned long long e2 = __builtin_nontemporal_load(eraw + jA + 2);
        unsigned long long e3 = __builtin_nontemporal_load(eraw + jA + 3);
        float g0 = lrl[(size_t)((((int)e0) & 0x1FFFF) * HID)];
        float g1 = lrl[(size_t)((((int)e1) & 0x1FFFF) * HID)];
        float g2 = lrl[(size_t)((((int)e2) & 0x1FFFF) * HID)];
        float g3 = lrl[(size_t)((((int)e3) & 0x1FFFF) * HID)];
        STEP(e0, g0, curdA, aA); STEP(e1, g1, curdA, aA);
        STEP(e2, g2, curdA, aA); STEP(e3, g3, curdA, aA);
      }
      for (; jA < endA; ++jA) {
        unsigned long long e = __builtin_nontemporal_load(eraw + jA);
        float g = lrl[(size_t)((((int)e) & 0x1FFFF) * HID)];
        STEP(e, g, curdA, aA);
      }
      FLUSH(curdA, aA);
      // drain chain B
      for (; jB + 4 <= endB; jB += 4) {
        unsigned long long f0 = __builtin_nontemporal_load(eraw + jB + 0);
        unsigned long long f1 = __builtin_nontemporal_load(eraw + jB + 1);
        unsigned long long f2 = __builtin_nontemporal_load(eraw + jB + 2);
        unsigned long long f3 = __builtin_nontemporal_load(eraw + jB + 3);
        float q0 = lrl[(size_t)((((int)f0) & 0x1FFFF) * HID)];
        float q1 = lrl[(size_t)((((int)f1) & 0x1FFFF) * HID)];
        float q2 = lrl[(size_t)((((int)f2) & 0x1FFFF) * HID)];
        float q3 = lrl[(size_t)((((int)f3) & 0x1FFFF) * HID)];
        STEP(f0, q0, curdB, aB); STEP(f1, q1, curdB, aB);
        STEP(f2, q2, curdB, aB); STEP(f3, q3, curdB, aB);
      }
      for (; jB < endB; ++jB) {
        unsigned long long f = __builtin_nontemporal_load(eraw + jB);
        float q = lrl[(size_t)((((int)f) & 0x1FFFF) * HID)];
        STEP(f, q, curdB, aB);
      }
      FLUSH(curdB, aB);
    }
  }
#undef STEP
#undef FLUSH

  float d1 = 0.f, d2 = 0.f;
#pragma unroll
  for (int d = 0; d < RPW; ++d) {
    const int n = rlo + d;
    if (n < N_NODES) {
      size_t o = (size_t)n * HID + lane;
      float a = acc[d] * sig;
      float l = lastr[o];
      float s = __builtin_nontemporal_load(secondr + o);
      __builtin_nontemporal_store(a, h + o);
      d1 = fmaf(a, l, d1);
      d2 = fmaf(a, s, d2);
    }
  }
  atomicAdd(&red[lane], d1);
  atomicAdd(&red[64 + lane], d2);
  __syncthreads();
  if (t < 128) atomicAdd(&dslot[t], red[t]);
}

// ---------------- passB ----------------
__launch_bounds__(256)
__global__ void passB_kernel(float4* __restrict__ h4, const float4* __restrict__ l4,
                             const float4* __restrict__ s4, float* __restrict__ dcur,
                             const float* __restrict__ nn_l, const float* __restrict__ nn_s,
                             const float* __restrict__ alpha, int prevcol, int accum,
                             float4* __restrict__ rst4) {
  __shared__ float red[64];
  int t = threadIdx.x;
  int q = t & 15;
  int c0 = q * 4;
  float4 NL = ((const float4*)nn_l)[q];
  float4 NS = ((const float4*)nn_s)[q];
  float4 D1 = ((const float4*)dcur)[q];
  float4 D2 = ((const float4*)(dcur + 64))[q];
  float4 sigl, sigs;
  sigl.x = 1.f / fmaxf(sqrtf(NL.x), 1e-8f); sigl.y = 1.f / fmaxf(sqrtf(NL.y), 1e-8f);
  sigl.z = 1.f / fmaxf(sqrtf(NL.z), 1e-8f); sigl.w = 1.f / fmaxf(sqrtf(NL.w), 1e-8f);
  sigs.x = 1.f / fmaxf(sqrtf(NS.x), 1e-8f); sigs.y = 1.f / fmaxf(sqrtf(NS.y), 1e-8f);
  sigs.z = 1.f / fmaxf(sqrtf(NS.z), 1e-8f); sigs.w = 1.f / fmaxf(sqrtf(NS.w), 1e-8f);
  float4 C1, C2, AL;
  C1.x = sigl.x * sigl.x * D1.x; C1.y = sigl.y * sigl.y * D1.y;
  C1.z = sigl.z * sigl.z * D1.z; C1.w = sigl.w * sigl.w * D1.w;
  C2.x = sigs.x * sigs.x * D2.x; C2.y = sigs.y * sigs.y * D2.y;
  C2.z = sigs.z * sigs.z * D2.z; C2.w = sigs.w * sigs.w * D2.w;
  AL.x = alpha[(size_t)(c0 + 0) * (KHOPS + 1) + prevcol] * sigl.x;
  AL.y = alpha[(size_t)(c0 + 1) * (KHOPS + 1) + prevcol] * sigl.y;
  AL.z = alpha[(size_t)(c0 + 2) * (KHOPS + 1) + prevcol] * sigl.z;
  AL.w = alpha[(size_t)(c0 + 3) * (KHOPS + 1) + prevcol] * sigl.w;
  float nx = 0.f, ny = 0.f, nz = 0.f, nw = 0.f;
  int row0 = blockIdx.x * 16 + (t >> 4);
  int rstride = gridDim.x * 16;
  for (int n = row0; n < N_NODES; n += rstride) {
    size_t idx = (size_t)n * 16 + q;
    float4 h = h4[idx];
    float4 l = l4[idx];
    float4 s = s4[idx];
    h.x -= C1.x * l.x + C2.x * s.x;
    h.y -= C1.y * l.y + C2.y * s.y;
    h.z -= C1.z * l.z + C2.z * s.z;
    h.w -= C1.w * l.w + C2.w * s.w;
    h4[idx] = h;
    nx = fmaf(h.x, h.x, nx); ny = fmaf(h.y, h.y, ny);
    nz = fmaf(h.z, h.z, nz); nw = fmaf(h.w, h.w, nw);
    float4 r;
    if (accum) {
      r = rst4[idx];
      r.x = fmaf(AL.x, l.x, r.x); r.y = fmaf(AL.y, l.y, r.y);
      r.z = fmaf(AL.z, l.z, r.z); r.w = fmaf(AL.w, l.w, r.w);
    } else {
      r.x = AL.x * l.x; r.y = AL.y * l.y; r.z = AL.z * l.z; r.w = AL.w * l.w;
    }
    rst4[idx] = r;
  }
  if (t < 64) red[t] = 0.f;
  __syncthreads();
  atomicAdd(&red[c0 + 0], nx); atomicAdd(&red[c0 + 1], ny);
  atomicAdd(&red[c0 + 2], nz); atomicAdd(&red[c0 + 3], nw);
  __syncthreads();
  if (t < 64) atomicAdd(&dcur[128 + t], red[t]);
}

// ---------------- fc2 ----------------
__launch_bounds__(256)
__global__ void gemm2_kernel(const float* __restrict__ rst, const float* __restrict__ hK,
                             const float* __restrict__ nnK, const float* __restrict__ alpha,
                             const float* __restrict__ W2, const float* __restrict__ bias2,
                             float* __restrict__ out) {
  __shared__ float W2s[HID * CLS];
  __shared__ float R[64][65];
  __shared__ float coef[64];
  int t = threadIdx.x;
  if (t < 64) coef[t] = alpha[(size_t)t * (KHOPS + 1) + KHOPS] / fmaxf(sqrtf(nnK[t]), 1e-8f);
  for (int i = t; i < HID * CLS; i += 256) W2s[i] = W2[i];
  int nodeBase = blockIdx.x * 64;
  __syncthreads();
  for (int i = t; i < 64 * 16; i += 256) {
    int r = i >> 4, c4 = (i & 15) * 4;
    int n = nodeBase + r;
    if (n < N_NODES) {
      float4 rv = *(const float4*)(rst + (size_t)n * HID + c4);
      float4 hv = *(const float4*)(hK + (size_t)n * HID + c4);
      R[r][c4 + 0] = rv.x + coef[c4 + 0] * hv.x;
      R[r][c4 + 1] = rv.y + coef[c4 + 1] * hv.y;
      R[r][c4 + 2] = rv.z + coef[c4 + 2] * hv.z;
      R[r][c4 + 3] = rv.w + coef[c4 + 3] * hv.w;
    } else {
      R[r][c4 + 0] = 0.f; R[r][c4 + 1] = 0.f; R[r][c4 + 2] = 0.f; R[r][c4 + 3] = 0.f;
    }
  }
  __syncthreads();
  int node = t >> 2;
  int cls0 = (t & 3) * 10;
  float o[10];
#pragma unroll
  for (int j = 0; j < 10; ++j) o[j] = bias2[cls0 + j];
#pragma unroll 4
  for (int k = 0; k < HID; ++k) {
    float rv = R[node][k];
    const float* wrow = &W2s[k * CLS + cls0];
#pragma unroll
    for (int j = 0; j < 10; ++j) o[j] = fmaf(rv, wrow[j], o[j]);
  }
  int n = nodeBase + node;
  if (n < N_NODES) {
#pragma unroll
    for (int j = 0; j < 10; ++j) out[(size_t)n * CLS + cls0 + j] = o[j];
  }
}

extern "C" void kernel_launch(void* const* d_in, const int* in_sizes, int n_in,
                              void* d_out, int out_size, void* d_ws, size_t ws_size,
                              hipStream_t stream) {
  (void)in_sizes; (void)n_in; (void)out_size;
  const float* features  = (const float*)d_in[0];
  const float* noise     = (const float*)d_in[1];
  const float* norm_A    = (const float*)d_in[2];
  const float* W1        = (const float*)d_in[3];
  const float* b1        = (const float*)d_in[4];
  const float* W2        = (const float*)d_in[5];
  const float* b2        = (const float*)d_in[6];
  const float* alpha     = (const float*)d_in[7];
  const int*   edge_index= (const int*)d_in[8];
  float* out = (float*)d_out;

  char* ws = (char*)d_ws;
  const size_t NB = (size_t)N_NODES * HID * sizeof(float);   // 25,600,000
  const size_t OFF2_BYTES = 5200128;                          // (NOFF2+1)*4 padded
  const size_t DOTS_BYTES = (size_t)12 * 192 * 4;             // 9216
  float* hA    = (float*)(ws);
  float* hC    = (float*)(ws + NB);
  float* rst   = (float*)(ws + 2 * NB);
  int2*  edges = (int2*)(ws + 3 * NB);
  char*  zbase = ws + 4 * NB;
  float* hB    = (float*)(zbase);                             // zeroed -> initial "second"
  int*   off2  = (int*)(zbase + NB);                          // zeroed -> hist bins
  float* dots  = (float*)(zbase + NB + OFF2_BYTES);           // zeroed
  const size_t zspan = NB + OFF2_BYTES + DOTS_BYTES;          // mult of 16
  int*   psum  = (int*)(zbase + zspan);                       // SCAN_NBLK2 ints
  // cursor2 overlays rst: rst is first written by passB(i=1) with accum=0 (pure
  // overwrite), which happens strictly after fill completes on this stream.
  int*   cursor2 = (int*)rst;
  const size_t total = 4 * NB + zspan + 20480;
  if (ws_size < total) return;

  zero_kernel<<<4096, 256, 0, stream>>>((float4*)zbase, zspan / 16);
  hist_kernel<<<2048, 256, 0, stream>>>(edge_index, edge_index + N_EDGES, off2);
  scanA_kernel<<<SCAN_NBLK2, SCAN_BS, 0, stream>>>(off2, psum);
  scanB_kernel<<<1, SCANB_T, 0, stream>>>(psum);
  scanC_kernel<<<SCAN_NBLK2, SCAN_BS, 0, stream>>>(off2, cursor2, psum);
  fill_kernel<<<2048, 256, 0, stream>>>(edge_index, edge_index + N_EDGES, norm_A, cursor2, edges);
  fc1_kernel<<<(N_NODES + 127) / 128, 256, 0, stream>>>(features, W1, b1, noise, hA,
                                                        dots + 1 * 192 + 128);
  float* second = hB; float* last = hA; float* cur = hC;
  for (int i = 1; i <= KHOPS; ++i) {
    float* dc = dots + (size_t)(i + 1) * 192;
    float* nl = dots + (size_t)(i)     * 192 + 128;
    float* ns = dots + (size_t)(i - 1) * 192 + 128;
    spmm_kernel<<<2048, 256, 0, stream>>>(edges, off2, last, second, nl, cur, dc);
    passB_kernel<<<1024, 256, 0, stream>>>((float4*)cur, (const float4*)last,
                                           (const float4*)second, dc, nl, ns,
                                           alpha, i - 1, (i > 1) ? 1 : 0, (float4*)rst);
    float* tmp = second; second = last; last = cur; cur = tmp;
  }
  gemm2_kernel<<<(N_NODES + 63) / 64, 256, 0, stream>>>(rst, last,
                                                        dots + (size_t)(KHOPS + 1) * 192 + 128,
                                                        alpha, W2, b2, out);
}

// Round 6
// 2394.248 us; speedup vs baseline: 5.1368x; 1.0740x over previous
//
#include <hip/hip_runtime.h>
#include <stdint.h>

#define N_NODES 100000
#define N_EDGES 3200000
#define IN_FEATS 500
#define HID 64
#define CLS 40
#define KHOPS 10
#define KT 32
#define NRANGE 8
#define NBKT 13          // src buckets: src>>13, 8192 nodes = 2MB of lastr per bucket
#define BSHIFT 13
#define RPW 13           // dst rows per wave (8192 waves x 13 >= 100000)
#define NOFF2 (N_NODES * NBKT)       // 1,300,000 (bucket,dst) bins
#define M2 (NOFF2 + 1)               // scan length
#define SCAN_BS 256
#define SCAN_NBLK2 ((M2 + SCAN_BS - 1) / SCAN_BS)   // 5079
#define SCANB_T 1024
#define SCANB_CH ((SCAN_NBLK2 + SCANB_T - 1) / SCANB_T)  // 5
#define SENT 0x7fc0dead  // NaN payload: unreachable as a finite running sum

// ---------------- generic zero ----------------
__global__ void zero_kernel(float4* __restrict__ p, size_t n4) {
  size_t i = (size_t)blockIdx.x * blockDim.x + threadIdx.x;
  size_t stride = (size_t)gridDim.x * blockDim.x;
  float4 z = make_float4(0.f, 0.f, 0.f, 0.f);
  for (; i < n4; i += stride) p[i] = z;
}

// ---------------- CSR build over (bucket, dst) keys ----------------
__global__ void hist_kernel(const int* __restrict__ src, const int* __restrict__ dst,
                            int* __restrict__ off2) {
  const int r = blockIdx.x & (NRANGE - 1);
  const int slice = blockIdx.x >> 3;
  const int nslices = gridDim.x >> 3;
  const int lo = r * (N_NODES / NRANGE);
  const int hi = lo + (N_NODES / NRANGE);
  const int per = (N_EDGES + nslices - 1) / nslices;
  const int beg = slice * per;
  int end = beg + per; if (end > N_EDGES) end = N_EDGES;
  for (int e = beg + threadIdx.x; e < end; e += blockDim.x) {
    int s = __builtin_nontemporal_load(src + e);
    if (s >= lo && s < hi) {
      int d = __builtin_nontemporal_load(dst + e);
      atomicAdd(&off2[(s >> BSHIFT) * N_NODES + d + 1], 1);
    }
  }
}

__launch_bounds__(SCAN_BS)
__global__ void scanA_kernel(const int* __restrict__ off2, int* __restrict__ psum) {
  __shared__ int s[SCAN_BS];
  int b = blockIdx.x, t = threadIdx.x;
  int idx = b * SCAN_BS + t;
  s[t] = (idx < M2) ? off2[idx] : 0;
  __syncthreads();
  for (int d = SCAN_BS / 2; d > 0; d >>= 1) {
    if (t < d) s[t] += s[t + d];
    __syncthreads();
  }
  if (t == 0) psum[b] = s[0];
}

__launch_bounds__(SCANB_T)
__global__ void scanB_kernel(int* __restrict__ psum) {
  __shared__ int s[SCANB_T];
  int t = threadIdx.x;
  int base = t * SCANB_CH;
  int v[SCANB_CH];
  int sum = 0;
#pragma unroll
  for (int k = 0; k < SCANB_CH; ++k) {
    int i = base + k;
    v[k] = (i < SCAN_NBLK2) ? psum[i] : 0;
    sum += v[k];
  }
  s[t] = sum;
  __syncthreads();
  for (int d = 1; d < SCANB_T; d <<= 1) {
    int x = (t >= d) ? s[t - d] : 0;
    __syncthreads();
    s[t] += x;
    __syncthreads();
  }
  int run = (t == 0) ? 0 : s[t - 1];
#pragma unroll
  for (int k = 0; k < SCANB_CH; ++k) {
    int i = base + k;
    if (i < SCAN_NBLK2) { psum[i] = run; run += v[k]; }
  }
}

__launch_bounds__(SCAN_BS)
__global__ void scanC_kernel(int* __restrict__ off2, int* __restrict__ cursor2,
                             const int* __restrict__ psum) {
  __shared__ int s[SCAN_BS];
  int b = blockIdx.x, t = threadIdx.x;
  int idx = b * SCAN_BS + t;
  s[t] = (idx < M2) ? off2[idx] : 0;
  __syncthreads();
  for (int d = 1; d < SCAN_BS; d <<= 1) {
    int v = (t >= d) ? s[t - d] : 0;
    __syncthreads();
    s[t] += v;
    __syncthreads();
  }
  int run = s[t] + psum[b];
  if (idx < M2) {
    off2[idx] = run;
    if (idx < NOFF2) cursor2[idx] = run;
  }
}

// fill: src-range partitioned; edge payload packs row-tag (dst%13) into bits 17..20.
__global__ void fill_kernel(const int* __restrict__ src, const int* __restrict__ dst,
                            const float* __restrict__ w, int* __restrict__ cursor2,
                            int2* __restrict__ edges) {
  const int r = blockIdx.x & (NRANGE - 1);
  const int slice = blockIdx.x >> 3;
  const int nslices = gridDim.x >> 3;
  const int lo = r * (N_NODES / NRANGE);
  const int hi = lo + (N_NODES / NRANGE);
  const int per = (N_EDGES + nslices - 1) / nslices;
  const int beg = slice * per;
  int end = beg + per; if (end > N_EDGES) end = N_EDGES;
  for (int e = beg + threadIdx.x; e < end; e += blockDim.x) {
    int s = __builtin_nontemporal_load(src + e);
    if (s >= lo && s < hi) {
      int d = __builtin_nontemporal_load(dst + e);
      float wv = __builtin_nontemporal_load(w + e);
      int p = atomicAdd(&cursor2[(s >> BSHIFT) * N_NODES + d], 1);
      int tag = d % RPW;                       // row index within owning wave
      edges[p] = make_int2((tag << 17) | s, __float_as_int(wv));
    }
  }
}

// ---------------- fc1 ----------------
__launch_bounds__(256)
__global__ void fc1_kernel(const float* __restrict__ F, const float* __restrict__ W1,
                           const float* __restrict__ bias1, const float* __restrict__ noise,
                           float* __restrict__ x, float* __restrict__ nn0) {
  __shared__ float Fs[KT][132];
  __shared__ float Ws[KT][64];
  __shared__ float red[64];
  const int t = threadIdx.x;
  const int tx = t & 15;
  const int ty = t >> 4;
  const int c0 = tx * 4;
  const int n0 = ty * 8;
  const int nodeBase = blockIdx.x * 128;
  const int fk = (t & 7) * 4;
  const int fn = t >> 3;
  const int wr = t >> 3;
  const int wc = (t & 7) * 8;

  float4 fr[4];
  float4 w0r, w1r;
  {
#pragma unroll
    for (int p = 0; p < 4; ++p) {
      int n = nodeBase + fn + 32 * p;
      float4 v = make_float4(0.f, 0.f, 0.f, 0.f);
      if (n < N_NODES && fk + 3 < IN_FEATS) v = *(const float4*)(F + (size_t)n * IN_FEATS + fk);
      fr[p] = v;
    }
    float4 a = make_float4(0.f, 0.f, 0.f, 0.f), b = a;
    if (wr < IN_FEATS) {
      a = *(const float4*)(W1 + (size_t)wr * HID + wc);
      b = *(const float4*)(W1 + (size_t)wr * HID + wc + 4);
    }
    w0r = a; w1r = b;
  }

  float acc[8][4];
#pragma unroll
  for (int i = 0; i < 8; ++i)
#pragma unroll
    for (int j = 0; j < 4; ++j) acc[i][j] = 0.f;

  const int NTILE = (IN_FEATS + KT - 1) / KT;
  for (int tile = 0; tile < NTILE; ++tile) {
    __syncthreads();
#pragma unroll
    for (int p = 0; p < 4; ++p) {
      Fs[fk + 0][fn + 32 * p] = fr[p].x;
      Fs[fk + 1][fn + 32 * p] = fr[p].y;
      Fs[fk + 2][fn + 32 * p] = fr[p].z;
      Fs[fk + 3][fn + 32 * p] = fr[p].w;
    }
    *(float4*)&Ws[wr][wc] = w0r;
    *(float4*)&Ws[wr][wc + 4] = w1r;
    __syncthreads();
    if (tile + 1 < NTILE) {
      const int kb = (tile + 1) * KT;
#pragma unroll
      for (int p = 0; p < 4; ++p) {
        int n = nodeBase + fn + 32 * p;
        int k = kb + fk;
        float4 v = make_float4(0.f, 0.f, 0.f, 0.f);
        if (n < N_NODES && k + 3 < IN_FEATS) v = *(const float4*)(F + (size_t)n * IN_FEATS + k);
        fr[p] = v;
      }
      int k = kb + wr;
      float4 a = make_float4(0.f, 0.f, 0.f, 0.f), b = a;
      if (k < IN_FEATS) {
        a = *(const float4*)(W1 + (size_t)k * HID + wc);
        b = *(const float4*)(W1 + (size_t)k * HID + wc + 4);
      }
      w0r = a; w1r = b;
    }
#pragma unroll 8
    for (int kk = 0; kk < KT; ++kk) {
      float4 fa = *(float4*)&Fs[kk][n0];
      float4 fb = *(float4*)&Fs[kk][n0 + 4];
      float4 wv = *(float4*)&Ws[kk][c0];
      acc[0][0] = fmaf(fa.x, wv.x, acc[0][0]); acc[0][1] = fmaf(fa.x, wv.y, acc[0][1]);
      acc[0][2] = fmaf(fa.x, wv.z, acc[0][2]); acc[0][3] = fmaf(fa.x, wv.w, acc[0][3]);
      acc[1][0] = fmaf(fa.y, wv.x, acc[1][0]); acc[1][1] = fmaf(fa.y, wv.y, acc[1][1]);
      acc[1][2] = fmaf(fa.y, wv.z, acc[1][2]); acc[1][3] = fmaf(fa.y, wv.w, acc[1][3]);
      acc[2][0] = fmaf(fa.z, wv.x, acc[2][0]); acc[2][1] = fmaf(fa.z, wv.y, acc[2][1]);
      acc[2][2] = fmaf(fa.z, wv.z, acc[2][2]); acc[2][3] = fmaf(fa.z, wv.w, acc[2][3]);
      acc[3][0] = fmaf(fa.w, wv.x, acc[3][0]); acc[3][1] = fmaf(fa.w, wv.y, acc[3][1]);
      acc[3][2] = fmaf(fa.w, wv.z, acc[3][2]); acc[3][3] = fmaf(fa.w, wv.w, acc[3][3]);
      acc[4][0] = fmaf(fb.x, wv.x, acc[4][0]); acc[4][1] = fmaf(fb.x, wv.y, acc[4][1]);
      acc[4][2] = fmaf(fb.x, wv.z, acc[4][2]); acc[4][3] = fmaf(fb.x, wv.w, acc[4][3]);
      acc[5][0] = fmaf(fb.y, wv.x, acc[5][0]); acc[5][1] = fmaf(fb.y, wv.y, acc[5][1]);
      acc[5][2] = fmaf(fb.y, wv.z, acc[5][2]); acc[5][3] = fmaf(fb.y, wv.w, acc[5][3]);
      acc[6][0] = fmaf(fb.z, wv.x, acc[6][0]); acc[6][1] = fmaf(fb.z, wv.y, acc[6][1]);
      acc[6][2] = fmaf(fb.z, wv.z, acc[6][2]); acc[6][3] = fmaf(fb.z, wv.w, acc[6][3]);
      acc[7][0] = fmaf(fb.w, wv.x, acc[7][0]); acc[7][1] = fmaf(fb.w, wv.y, acc[7][1]);
      acc[7][2] = fmaf(fb.w, wv.z, acc[7][2]); acc[7][3] = fmaf(fb.w, wv.w, acc[7][3]);
    }
  }

  float4 bb = *(const float4*)(bias1 + c0);
  float np0 = 0.f, np1 = 0.f, np2 = 0.f, np3 = 0.f;
#pragma unroll
  for (int i = 0; i < 8; ++i) {
    int n = nodeBase + n0 + i;
    if (n < N_NODES) {
      float4 nz = *(const float4*)(noise + (size_t)n * HID + c0);
      float v0 = fmaxf(acc[i][0] + bb.x, 0.f) + nz.x * 1e-5f;
      float v1 = fmaxf(acc[i][1] + bb.y, 0.f) + nz.y * 1e-5f;
      float v2 = fmaxf(acc[i][2] + bb.z, 0.f) + nz.z * 1e-5f;
      float v3 = fmaxf(acc[i][3] + bb.w, 0.f) + nz.w * 1e-5f;
      *(float4*)(x + (size_t)n * HID + c0) = make_float4(v0, v1, v2, v3);
      np0 = fmaf(v0, v0, np0); np1 = fmaf(v1, v1, np1);
      np2 = fmaf(v2, v2, np2); np3 = fmaf(v3, v3, np3);
    }
  }
  if (t < 64) red[t] = 0.f;
  __syncthreads();
  atomicAdd(&red[c0 + 0], np0); atomicAdd(&red[c0 + 1], np1);
  atomicAdd(&red[c0 + 2], np2); atomicAdd(&red[c0 + 3], np3);
  __syncthreads();
  if (t < 64) atomicAdd(&nn0[t], red[t]);
}

// ---------------- SpMM: bucket-major sweep, branch-free prefix-sum routing ----
// Wave w owns 13 consecutive dst rows; edges sorted by (bucket,dst) give ONE
// contiguous range per (wave,bucket) with MONOTONE row tags. Inner loop is pure
// straight-line: running = fmaf(w, gather, running); ds_write bnd[tag] = running
// (last-write-wins = prefix total through that tag's run). Per bucket end:
// acc[d] += bnd[d] - bnd[d-1] with sentinel carry-forward for absent tags.
// No branches, no atomics, no readfirstlane in the edge loop.
__launch_bounds__(256, 8)
__global__ void spmm_kernel(const int2* __restrict__ edges, const int* __restrict__ off2,
                            const float* __restrict__ lastr, const float* __restrict__ secondr,
                            const float* __restrict__ nn_l,
                            float* __restrict__ h, float* __restrict__ dslot) {
  __shared__ float bnd_s[4 * RPW * 64];   // 13312 B: [wave][tag][lane]
  __shared__ float red[128];
  const int t = threadIdx.x;
  const int lane = t & 63;
  const int wid = t >> 6;
  float* __restrict__ bnd = &bnd_s[(wid * RPW) * 64 + lane];  // wave-private slice
  if (t < 128) red[t] = 0.f;
  __syncthreads();

  const float sig = 1.f / fmaxf(sqrtf(nn_l[lane]), 1e-8f);
  const int w = blockIdx.x * 4 + wid;   // 0..8191
  const int rlo = w * RPW;
  const unsigned long long* __restrict__ eraw = (const unsigned long long*)edges;
  const float* __restrict__ lrl = lastr + lane;
  const float sentf = __int_as_float(SENT);

  float acc[RPW];
#pragma unroll
  for (int d = 0; d < RPW; ++d) acc[d] = 0.f;

  if (rlo < N_NODES) {
    const int rhi = (rlo + RPW < N_NODES) ? rlo + RPW : N_NODES;
    for (int b = 0; b < NBKT; ++b) {
      const int kb = b * N_NODES;
      const int beg = __builtin_amdgcn_readfirstlane(off2[kb + rlo]);
      const int end = __builtin_amdgcn_readfirstlane(off2[kb + rhi]);
#pragma unroll
      for (int d = 0; d < RPW; ++d) bnd[d * 64] = sentf;   // sentinel init
      float running = 0.f;
      int j = beg;
      for (; j + 4 <= end; j += 4) {
        unsigned long long e0 = __builtin_nontemporal_load(eraw + j + 0);
        unsigned long long e1 = __builtin_nontemporal_load(eraw + j + 1);
        unsigned long long e2 = __builtin_nontemporal_load(eraw + j + 2);
        unsigned long long e3 = __builtin_nontemporal_load(eraw + j + 3);
        int l0 = (int)e0, l1 = (int)e1, l2 = (int)e2, l3 = (int)e3;
        float g0 = lrl[(size_t)((l0 & 0x1FFFF) * HID)];
        float g1 = lrl[(size_t)((l1 & 0x1FFFF) * HID)];
        float g2 = lrl[(size_t)((l2 & 0x1FFFF) * HID)];
        float g3 = lrl[(size_t)((l3 & 0x1FFFF) * HID)];
        running = fmaf(__int_as_float((int)(e0 >> 32)), g0, running);
        bnd[(l0 >> 17) * 64] = running;
        running = fmaf(__int_as_float((int)(e1 >> 32)), g1, running);
        bnd[(l1 >> 17) * 64] = running;
        running = fmaf(__int_as_float((int)(e2 >> 32)), g2, running);
        bnd[(l2 >> 17) * 64] = running;
        running = fmaf(__int_as_float((int)(e3 >> 32)), g3, running);
        bnd[(l3 >> 17) * 64] = running;
      }
      for (; j < end; ++j) {
        unsigned long long e = __builtin_nontemporal_load(eraw + j);
        int l0 = (int)e;
        float g = lrl[(size_t)((l0 & 0x1FFFF) * HID)];
        running = fmaf(__int_as_float((int)(e >> 32)), g, running);
        bnd[(l0 >> 17) * 64] = running;
      }
      // diff-extract with sentinel carry-forward (static unroll, wave-private)
      float prev = 0.f;
#pragma unroll
      for (int d = 0; d < RPW; ++d) {
        float v = bnd[d * 64];
        v = (__float_as_int(v) == SENT) ? prev : v;
        acc[d] += v - prev;
        prev = v;
      }
    }
  }

  float d1 = 0.f, d2 = 0.f;
#pragma unroll
  for (int d = 0; d < RPW; ++d) {
    const int n = rlo + d;
    if (n < N_NODES) {
      size_t o = (size_t)n * HID + lane;
      float a = acc[d] * sig;
      float l = lastr[o];
      float s = __builtin_nontemporal_load(secondr + o);
      __builtin_nontemporal_store(a, h + o);
      d1 = fmaf(a, l, d1);
      d2 = fmaf(a, s, d2);
    }
  }
  atomicAdd(&red[lane], d1);
  atomicAdd(&red[64 + lane], d2);
  __syncthreads();
  if (t < 128) atomicAdd(&dslot[t], red[t]);
}

// ---------------- passB ----------------
__launch_bounds__(256)
__global__ void passB_kernel(float4* __restrict__ h4, const float4* __restrict__ l4,
                             const float4* __restrict__ s4, float* __restrict__ dcur,
                             const float* __restrict__ nn_l, const float* __restrict__ nn_s,
                             const float* __restrict__ alpha, int prevcol, int accum,
                             float4* __restrict__ rst4) {
  __shared__ float red[64];
  int t = threadIdx.x;
  int q = t & 15;
  int c0 = q * 4;
  float4 NL = ((const float4*)nn_l)[q];
  float4 NS = ((const float4*)nn_s)[q];
  float4 D1 = ((const float4*)dcur)[q];
  float4 D2 = ((const float4*)(dcur + 64))[q];
  float4 sigl, sigs;
  sigl.x = 1.f / fmaxf(sqrtf(NL.x), 1e-8f); sigl.y = 1.f / fmaxf(sqrtf(NL.y), 1e-8f);
  sigl.z = 1.f / fmaxf(sqrtf(NL.z), 1e-8f); sigl.w = 1.f / fmaxf(sqrtf(NL.w), 1e-8f);
  sigs.x = 1.f / fmaxf(sqrtf(NS.x), 1e-8f); sigs.y = 1.f / fmaxf(sqrtf(NS.y), 1e-8f);
  sigs.z = 1.f / fmaxf(sqrtf(NS.z), 1e-8f); sigs.w = 1.f / fmaxf(sqrtf(NS.w), 1e-8f);
  float4 C1, C2, AL;
  C1.x = sigl.x * sigl.x * D1.x; C1.y = sigl.y * sigl.y * D1.y;
  C1.z = sigl.z * sigl.z * D1.z; C1.w = sigl.w * sigl.w * D1.w;
  C2.x = sigs.x * sigs.x * D2.x; C2.y = sigs.y * sigs.y * D2.y;
  C2.z = sigs.z * sigs.z * D2.z; C2.w = sigs.w * sigs.w * D2.w;
  AL.x = alpha[(size_t)(c0 + 0) * (KHOPS + 1) + prevcol] * sigl.x;
  AL.y = alpha[(size_t)(c0 + 1) * (KHOPS + 1) + prevcol] * sigl.y;
  AL.z = alpha[(size_t)(c0 + 2) * (KHOPS + 1) + prevcol] * sigl.z;
  AL.w = alpha[(size_t)(c0 + 3) * (KHOPS + 1) + prevcol] * sigl.w;
  float nx = 0.f, ny = 0.f, nz = 0.f, nw = 0.f;
  int row0 = blockIdx.x * 16 + (t >> 4);
  int rstride = gridDim.x * 16;
  for (int n = row0; n < N_NODES; n += rstride) {
    size_t idx = (size_t)n * 16 + q;
    float4 h = h4[idx];
    float4 l = l4[idx];
    float4 s = s4[idx];
    h.x -= C1.x * l.x + C2.x * s.x;
    h.y -= C1.y * l.y + C2.y * s.y;
    h.z -= C1.z * l.z + C2.z * s.z;
    h.w -= C1.w * l.w + C2.w * s.w;
    h4[idx] = h;
    nx = fmaf(h.x, h.x, nx); ny = fmaf(h.y, h.y, ny);
    nz = fmaf(h.z, h.z, nz); nw = fmaf(h.w, h.w, nw);
    float4 r;
    if (accum) {
      r = rst4[idx];
      r.x = fmaf(AL.x, l.x, r.x); r.y = fmaf(AL.y, l.y, r.y);
      r.z = fmaf(AL.z, l.z, r.z); r.w = fmaf(AL.w, l.w, r.w);
    } else {
      r.x = AL.x * l.x; r.y = AL.y * l.y; r.z = AL.z * l.z; r.w = AL.w * l.w;
    }
    rst4[idx] = r;
  }
  if (t < 64) red[t] = 0.f;
  __syncthreads();
  atomicAdd(&red[c0 + 0], nx); atomicAdd(&red[c0 + 1], ny);
  atomicAdd(&red[c0 + 2], nz); atomicAdd(&red[c0 + 3], nw);
  __syncthreads();
  if (t < 64) atomicAdd(&dcur[128 + t], red[t]);
}

// ---------------- fc2 ----------------
__launch_bounds__(256)
__global__ void gemm2_kernel(const float* __restrict__ rst, const float* __restrict__ hK,
                             const float* __restrict__ nnK, const float* __restrict__ alpha,
                             const float* __restrict__ W2, const float* __restrict__ bias2,
                             float* __restrict__ out) {
  __shared__ float W2s[HID * CLS];
  __shared__ float R[64][65];
  __shared__ float coef[64];
  int t = threadIdx.x;
  if (t < 64) coef[t] = alpha[(size_t)t * (KHOPS + 1) + KHOPS] / fmaxf(sqrtf(nnK[t]), 1e-8f);
  for (int i = t; i < HID * CLS; i += 256) W2s[i] = W2[i];
  int nodeBase = blockIdx.x * 64;
  __syncthreads();
  for (int i = t; i < 64 * 16; i += 256) {
    int r = i >> 4, c4 = (i & 15) * 4;
    int n = nodeBase + r;
    if (n < N_NODES) {
      float4 rv = *(const float4*)(rst + (size_t)n * HID + c4);
      float4 hv = *(const float4*)(hK + (size_t)n * HID + c4);
      R[r][c4 + 0] = rv.x + coef[c4 + 0] * hv.x;
      R[r][c4 + 1] = rv.y + coef[c4 + 1] * hv.y;
      R[r][c4 + 2] = rv.z + coef[c4 + 2] * hv.z;
      R[r][c4 + 3] = rv.w + coef[c4 + 3] * hv.w;
    } else {
      R[r][c4 + 0] = 0.f; R[r][c4 + 1] = 0.f; R[r][c4 + 2] = 0.f; R[r][c4 + 3] = 0.f;
    }
  }
  __syncthreads();
  int node = t >> 2;
  int cls0 = (t & 3) * 10;
  float o[10];
#pragma unroll
  for (int j = 0; j < 10; ++j) o[j] = bias2[cls0 + j];
#pragma unroll 4
  for (int k = 0; k < HID; ++k) {
    float rv = R[node][k];
    const float* wrow = &W2s[k * CLS + cls0];
#pragma unroll
    for (int j = 0; j < 10; ++j) o[j] = fmaf(rv, wrow[j], o[j]);
  }
  int n = nodeBase + node;
  if (n < N_NODES) {
#pragma unroll
    for (int j = 0; j < 10; ++j) out[(size_t)n * CLS + cls0 + j] = o[j];
  }
}

extern "C" void kernel_launch(void* const* d_in, const int* in_sizes, int n_in,
                              void* d_out, int out_size, void* d_ws, size_t ws_size,
                              hipStream_t stream) {
  (void)in_sizes; (void)n_in; (void)out_size;
  const float* features  = (const float*)d_in[0];
  const float* noise     = (const float*)d_in[1];
  const float* norm_A    = (const float*)d_in[2];
  const float* W1        = (const float*)d_in[3];
  const float* b1        = (const float*)d_in[4];
  const float* W2        = (const float*)d_in[5];
  const float* b2        = (const float*)d_in[6];
  const float* alpha     = (const float*)d_in[7];
  const int*   edge_index= (const int*)d_in[8];
  float* out = (float*)d_out;

  char* ws = (char*)d_ws;
  const size_t NB = (size_t)N_NODES * HID * sizeof(float);   // 25,600,000
  const size_t OFF2_BYTES = 5200128;                          // (NOFF2+1)*4 padded
  const size_t DOTS_BYTES = (size_t)12 * 192 * 4;             // 9216
  float* hA    = (float*)(ws);
  float* hC    = (float*)(ws + NB);
  float* rst   = (float*)(ws + 2 * NB);
  int2*  edges = (int2*)(ws + 3 * NB);
  char*  zbase = ws + 4 * NB;
  float* hB    = (float*)(zbase);                             // zeroed -> initial "second"
  int*   off2  = (int*)(zbase + NB);                          // zeroed -> hist bins
  float* dots  = (float*)(zbase + NB + OFF2_BYTES);           // zeroed
  const size_t zspan = NB + OFF2_BYTES + DOTS_BYTES;          // mult of 16
  int*   psum  = (int*)(zbase + zspan);                       // SCAN_NBLK2 ints
  // cursor2 overlays rst: rst is first written by passB(i=1) with accum=0 (pure
  // overwrite), which happens strictly after fill completes on this stream.
  int*   cursor2 = (int*)rst;
  const size_t total = 4 * NB + zspan + 20480;
  if (ws_size < total) return;

  zero_kernel<<<4096, 256, 0, stream>>>((float4*)zbase, zspan / 16);
  hist_kernel<<<2048, 256, 0, stream>>>(edge_index, edge_index + N_EDGES, off2);
  scanA_kernel<<<SCAN_NBLK2, SCAN_BS, 0, stream>>>(off2, psum);
  scanB_kernel<<<1, SCANB_T, 0, stream>>>(psum);
  scanC_kernel<<<SCAN_NBLK2, SCAN_BS, 0, stream>>>(off2, cursor2, psum);
  fill_kernel<<<2048, 256, 0, stream>>>(edge_index, edge_index + N_EDGES, norm_A, cursor2, edges);
  fc1_kernel<<<(N_NODES + 127) / 128, 256, 0, stream>>>(features, W1, b1, noise, hA,
                                                        dots + 1 * 192 + 128);
  float* second = hB; float* last = hA; float* cur = hC;
  for (int i = 1; i <= KHOPS; ++i) {
    float* dc = dots + (size_t)(i + 1) * 192;
    float* nl = dots + (size_t)(i)     * 192 + 128;
    float* ns = dots + (size_t)(i - 1) * 192 + 128;
    spmm_kernel<<<2048, 256, 0, stream>>>(edges, off2, last, second, nl, cur, dc);
    passB_kernel<<<1024, 256, 0, stream>>>((float4*)cur, (const float4*)last,
                                           (const float4*)second, dc, nl, ns,
                                           alpha, i - 1, (i > 1) ? 1 : 0, (float4*)rst);
    float* tmp = second; second = last; last = cur; cur = tmp;
  }
  gemm2_kernel<<<(N_NODES + 63) / 64, 256, 0, stream>>>(rst, last,
                                                        dots + (size_t)(KHOPS + 1) * 192 + 128,
                                                        alpha, W2, b2, out);
}